// Round 7
// baseline (221.997 us; speedup 1.0000x reference)
//
#include <hip/hip_runtime.h>
#include <hip/hip_bf16.h>
#include <cstdint>

// LambdaLayer on MI355X. b=16, dim=256, n=m=1024, HEADS=4, DIM_K=16, DIM_V=32.
// Pipeline (3 launches, ws kept small: harness ws-poison fill costs ~0.9us/MB):
//   k_proj : per (b, px-tile 32): MFMA GEMM (112x256)@(256x32) -> qraw/kraw/vraw fp32.
//   k_mid  : blocks 0..95: BN stats -> scale/shift; v-channels also write vbn bf16.
//            blocks 96..351: softmax(kraw) + lamcraw = sm . vraw (BN folded later).
//   k_lamp : GEMM lam_p = pos^T(16384x1024) @ vbn^T(1024x512); A staged directly from
//            fp32 pos; double-buffered software pipeline (issue loads after barrier,
//            consume before next barrier -> barrier drain hidden under MFMA).
//            Epilogue: out = (q*sc+sh).(lam_p + sc*lamcraw+sh).
// R6 post-mortem: LDS-pointer array triggered "static initializer addrspacecast"
// compile error. Fix: flat shared array + integer offsets (runtime pointers OK).

typedef __attribute__((ext_vector_type(8))) __bf16 bf16x8;
typedef __attribute__((ext_vector_type(4))) float f32x4;

__device__ __forceinline__ unsigned short f2bf(float f) {
    unsigned u = __float_as_uint(f);
    u += 0x7fffu + ((u >> 16) & 1u);   // round-to-nearest-even
    return (unsigned short)(u >> 16);
}
__device__ __forceinline__ unsigned pk2(float a, float b) {
    return (unsigned)f2bf(a) | ((unsigned)f2bf(b) << 16);
}
__device__ __forceinline__ float bf2f(unsigned short h) {
    return __uint_as_float(((unsigned)h) << 16);
}
__device__ __forceinline__ void async16(const void* g, void* l) {
    __builtin_amdgcn_global_load_lds(
        (const __attribute__((address_space(1))) void*)g,
        (__attribute__((address_space(3))) void*)l, 16, 0, 0);
}

// ---------------------------------------------------------------- k_proj
// grid (32,16): 512 blocks (2/CU). Block = 128 ch x 32 px, K=256 in 8 steps of 32.
__global__ __launch_bounds__(256) void k_proj(const float* __restrict__ x,
                                              const float* __restrict__ wq,
                                              const float* __restrict__ wk,
                                              const float* __restrict__ wv,
                                              float* __restrict__ qraw,
                                              float* __restrict__ kraw,
                                              float* __restrict__ vraw) {
    int b = blockIdx.y;
    int px0 = blockIdx.x * 32;
    int t = threadIdx.x;
    int w = t >> 6, lane = t & 63;

    __shared__ __align__(16) unsigned short Al[128 * 32];  // [ch][32c], octet-swizzled
    __shared__ __align__(16) unsigned short Bl[32 * 34];   // [px][c], stride 34

    int ch = t >> 1, half = t & 1;
    const float* wsrc = nullptr;
    if (ch < 64)       wsrc = wq + ch * 256;
    else if (ch < 80)  wsrc = wk + (ch - 64) * 256;
    else if (ch < 112) wsrc = wv + (ch - 80) * 256;
    if (wsrc) wsrc += half * 16;
    int s2 = (ch >> 1) & 3;
    unsigned short* wdst0 = &Al[ch * 32 + (((half * 2) ^ s2) << 3)];
    unsigned short* wdst1 = &Al[ch * 32 + (((half * 2 + 1) ^ s2) << 3)];

    int wm = w >> 1, wn = w & 1;
    int rl = lane & 15, qq = lane >> 4;
    int sw = qq ^ ((rl >> 1) & 3);

    f32x4 acc[4];
#pragma unroll
    for (int i = 0; i < 4; ++i)
#pragma unroll
        for (int r = 0; r < 4; ++r) acc[i][r] = 0.f;

    const float* xb = x + (size_t)b * 262144 + px0;

    for (int kt = 0; kt < 8; ++kt) {
        int c0 = kt * 32;
        {
            uint4 d0, d1;
            if (wsrc) {
                float4 f0 = *(const float4*)(wsrc + c0);
                float4 f1 = *(const float4*)(wsrc + c0 + 4);
                float4 f2 = *(const float4*)(wsrc + c0 + 8);
                float4 f3 = *(const float4*)(wsrc + c0 + 12);
                d0.x = pk2(f0.x, f0.y); d0.y = pk2(f0.z, f0.w);
                d0.z = pk2(f1.x, f1.y); d0.w = pk2(f1.z, f1.w);
                d1.x = pk2(f2.x, f2.y); d1.y = pk2(f2.z, f2.w);
                d1.z = pk2(f3.x, f3.y); d1.w = pk2(f3.z, f3.w);
            } else {
                d0 = make_uint4(0, 0, 0, 0); d1 = d0;
            }
            *(uint4*)wdst0 = d0;
            *(uint4*)wdst1 = d1;
        }
#pragma unroll
        for (int rep = 0; rep < 2; ++rep) {
            int idx = rep * 256 + t;
            int px = idx & 31;
            int cp = idx >> 5;
            int c = c0 + cp * 2;
            float f0 = xb[(size_t)c * 1024 + px];
            float f1 = xb[(size_t)(c + 1) * 1024 + px];
            *(unsigned*)&Bl[px * 34 + cp * 2] = pk2(f0, f1);
        }
        __syncthreads();
        bf16x8 a[4], bb;
#pragma unroll
        for (int i = 0; i < 4; ++i) a[i] = *(const bf16x8*)&Al[((wm << 6) + (i << 4) + rl) * 32 + sw * 8];
        bb = *(const bf16x8*)&Bl[((wn << 4) + rl) * 34 + qq * 8];
#pragma unroll
        for (int i = 0; i < 4; ++i)
            acc[i] = __builtin_amdgcn_mfma_f32_16x16x32_bf16(a[i], bb, acc[i], 0, 0, 0);
        __syncthreads();
    }

#pragma unroll
    for (int i = 0; i < 4; ++i) {
        int px = px0 + (wn << 4) + rl;
#pragma unroll
        for (int r = 0; r < 4; ++r) {
            int c = (wm << 6) + (i << 4) + (qq << 2) + r;
            float val = acc[i][r];
            if (c < 64)       qraw[((size_t)b * 64 + c) * 1024 + px] = val;
            else if (c < 80)  kraw[((size_t)b * 16 + (c - 64)) * 1024 + px] = val;
            else if (c < 112) vraw[((size_t)b * 32 + (c - 80)) * 1024 + px] = val;
        }
    }
}

// ---------------------------------------------------------------- k_mid
__global__ __launch_bounds__(1024) void k_mid(const float* __restrict__ qraw,
                                              const float* __restrict__ kraw,
                                              const float* __restrict__ vraw,
                                              const float* __restrict__ gq, const float* __restrict__ bq,
                                              const float* __restrict__ gv, const float* __restrict__ bv,
                                              unsigned short* __restrict__ vbn,
                                              float* __restrict__ scaleArr, float* __restrict__ shiftArr,
                                              float* __restrict__ lamcraw) {
    int bx = blockIdx.x;
    int t = threadIdx.x;
    int w = t >> 6, lane = t & 63;
    __shared__ float redA[16], redB[16];
    __shared__ float bc[2];
    __shared__ float pr[16][32];

    if (bx < 96) {
        int ch = bx;
        const float* base;
        size_t bstride;
        if (ch < 64) { base = qraw + (size_t)ch * 1024; bstride = 65536; }
        else         { base = vraw + (size_t)(ch - 64) * 1024; bstride = 32768; }
        float s = 0.f, ss = 0.f;
#pragma unroll
        for (int b = 0; b < 16; ++b) { float v = base[b * bstride + t]; s += v; ss += v * v; }
#pragma unroll
        for (int off = 32; off; off >>= 1) { s += __shfl_down(s, off); ss += __shfl_down(ss, off); }
        if (lane == 0) { redA[w] = s; redB[w] = ss; }
        __syncthreads();
        if (t == 0) {
            s = 0.f; ss = 0.f;
#pragma unroll
            for (int i = 0; i < 16; ++i) { s += redA[i]; ss += redB[i]; }
            float mean = s * (1.f / 16384.f);
            float var = ss * (1.f / 16384.f) - mean * mean;   // biased (jnp.var)
            float g, be;
            if (ch < 64) { g = gq[ch]; be = bq[ch]; } else { g = gv[ch - 64]; be = bv[ch - 64]; }
            float sc = g * rsqrtf(var + 1e-5f);
            float sh = be - mean * sc;
            scaleArr[ch] = sc; shiftArr[ch] = sh;
            bc[0] = sc; bc[1] = sh;
        }
        __syncthreads();
        if (ch >= 64) {
            float sc = bc[0], sh = bc[1];
            int vch = ch - 64;
#pragma unroll
            for (int b = 0; b < 16; ++b) {
                size_t idx = ((size_t)b * 32 + vch) * 1024 + t;
                vbn[idx] = f2bf(vraw[idx] * sc + sh);
            }
        }
    } else {
        int idx = bx - 96;
        int b = idx >> 4, kch = idx & 15;
        float xv = kraw[((size_t)b * 16 + kch) * 1024 + t];
        float mx = xv;
#pragma unroll
        for (int off = 32; off; off >>= 1) mx = fmaxf(mx, __shfl_down(mx, off));
        if (lane == 0) redA[w] = mx;
        __syncthreads();
        mx = redA[0];
#pragma unroll
        for (int i = 1; i < 16; ++i) mx = fmaxf(mx, redA[i]);
        float e = __expf(xv - mx);
        float s = e;
#pragma unroll
        for (int off = 32; off; off >>= 1) s += __shfl_down(s, off);
        __syncthreads();
        if (lane == 0) redB[w] = s;
        __syncthreads();
        s = 0.f;
#pragma unroll
        for (int i = 0; i < 16; ++i) s += redB[i];
        float inv = 1.f / s;
        const float* vb = vraw + (size_t)b * 32768;
        for (int v = 0; v < 32; ++v) {
            float p = e * vb[(size_t)v * 1024 + t];
#pragma unroll
            for (int off = 32; off; off >>= 1) p += __shfl_down(p, off);
            if (lane == 0) pr[w][v] = p;
        }
        __syncthreads();
        if (t < 32) {
            float tot = 0.f;
#pragma unroll
            for (int i = 0; i < 16; ++i) tot += pr[i][t];
            lamcraw[((size_t)b * 16 + kch) * 32 + t] = inv * tot;
        }
    }
}

// ---------------------------------------------------------------- k_lamp
// GEMM M=16384 (rows n*16+k), N=512 (cols b*32+v), K=1024 (m).
// grid(128,4): ntile siblings share id%8 -> same XCD L2 (pos reuse 4x).
// Double-buffered pipeline, 1 barrier/iter:
//   barrier -> issue async16 B[next] + 8 dwordx4 A[next]->regs -> compute(cur)
//   -> pack+ds_write A[next]. Loads complete under the MFMA block, so the
//   barrier's vmcnt(0) drain is no longer latency-exposed.
// Buffer layout (shorts): buf k at k*16896; A at +0 (128*68), B at +8704 (8192).
__global__ __launch_bounds__(256) void k_lamp(const float* __restrict__ pos,
                                              const unsigned short* __restrict__ vbn,
                                              const float* __restrict__ qraw,
                                              const float* __restrict__ lamcraw,
                                              const float* __restrict__ scaleArr,
                                              const float* __restrict__ shiftArr,
                                              float* __restrict__ out) {
    int mtile = blockIdx.x;    // 0..127
    int ntile = blockIdx.y;    // 0..3
    int t = threadIdx.x;
    int w = t >> 6, lane = t & 63;

    __shared__ union {
        __align__(16) unsigned short flat[2 * 16896];   // 67584 B
        __align__(16) unsigned short Ybf[128 * 132];    // 33792 B overlays buf0
    } sm;
    const int BUF = 16896, BOFF = 8704;   // shorts

    // A staging: thread = (nl:3, k0:2, am:3); covers pos[mtile*8+nl][m-octet am][k0*4..+4).
    int nl = t >> 5;            // 0..7
    int k0 = (t >> 3) & 3;      // 0..3
    int am = t & 7;             // 0..7
    const float* pAg = pos + ((size_t)(mtile * 8 + nl)) * 16384 + am * 128 + k0 * 4;
    int arow0 = (nl * 16 + k0 * 4) * 68 + am * 8;   // short offset within A region

    // B staging via async16: rows srow + i*32, octet XOR-swizzled
    int srow = t >> 3;
    int jx = (t & 7) ^ (srow & 7);
    const unsigned short* pB = vbn + ((size_t)(ntile * 128) + srow) * 1024 + jx * 8;

    int wm = w >> 1, wn = w & 1;
    int rl = lane & 15, qq = lane >> 4;
    int abase[2], bbase[2];
#pragma unroll
    for (int ks = 0; ks < 2; ++ks) {
        abase[ks] = (wm * 64 + rl) * 68 + ((ks * 4 + qq) << 3);                       // A: stride 68
        bbase[ks] = BOFF + (wn * 64 + rl) * 64 + (((ks * 4 + qq) ^ (rl & 7)) << 3);   // B: stride 64 XOR
    }

    f32x4 acc[4][4];
#pragma unroll
    for (int i = 0; i < 4; ++i)
#pragma unroll
        for (int j = 0; j < 4; ++j)
#pragma unroll
            for (int r = 0; r < 4; ++r) acc[i][j][r] = 0.f;

    float4 fl[8];   // in-flight A fragment

    auto issueA = [&](int kt) {
        const float* ps = pAg + (size_t)kt * 1024;
#pragma unroll
        for (int i = 0; i < 8; ++i) fl[i] = *(const float4*)(ps + i * 16);
    };
    auto issueB = [&](int buf, int kt) {
        unsigned short* ldsB = &sm.flat[buf * BUF + BOFF + t * 8];
#pragma unroll
        for (int i = 0; i < 4; ++i)
            async16(pB + (size_t)i * 32 * 1024 + kt * 64, ldsB + i * 2048);
    };
    auto packA = [&](int buf) {
        unsigned short* Ab = &sm.flat[buf * BUF];
#pragma unroll
        for (int c = 0; c < 4; ++c) {
            uint2 d0, d1;
            d0.x = pk2(((const float*)&fl[0])[c], ((const float*)&fl[1])[c]);
            d0.y = pk2(((const float*)&fl[2])[c], ((const float*)&fl[3])[c]);
            d1.x = pk2(((const float*)&fl[4])[c], ((const float*)&fl[5])[c]);
            d1.y = pk2(((const float*)&fl[6])[c], ((const float*)&fl[7])[c]);
            *(uint2*)&Ab[arow0 + c * 68] = d0;
            *(uint2*)&Ab[arow0 + c * 68 + 4] = d1;
        }
    };

    // prologue: fully stage buf0 for kt=0
    issueB(0, 0);
    issueA(0);
    packA(0);

    for (int kt = 0; kt < 16; ++kt) {
        int cur = kt & 1, nxt = cur ^ 1;
        __syncthreads();   // drains prev ds_writes + async16 for cur buffer
        if (kt < 15) {
            issueB(nxt, kt + 1);   // in flight during compute
            issueA(kt + 1);        // in flight during compute
        }
        const unsigned short* base = &sm.flat[cur * BUF];
#pragma unroll
        for (int ks = 0; ks < 2; ++ks) {
            bf16x8 a[4], bb[4];
#pragma unroll
            for (int i = 0; i < 4; ++i) a[i]  = *(const bf16x8*)&base[abase[ks] + i * 16 * 68];
#pragma unroll
            for (int j = 0; j < 4; ++j) bb[j] = *(const bf16x8*)&base[bbase[ks] + j * 1024];
#pragma unroll
            for (int i = 0; i < 4; ++i)
#pragma unroll
                for (int j = 0; j < 4; ++j)
                    acc[i][j] = __builtin_amdgcn_mfma_f32_16x16x32_bf16(a[i], bb[j], acc[i][j], 0, 0, 0);
        }
        if (kt < 15) packA(nxt);   // loads completed under the MFMAs
    }

    // acc + (sc*lamcraw + sh) -> Ybf bf16 (stride 132).
    // Ybf overlays buf0; last compute (kt=15) read buf1 -> no barrier needed here.
    int b0 = ntile * 4;
#pragma unroll
    for (int j = 0; j < 4; ++j) {
        int col = (wn << 6) + (j << 4) + rl;
        int bcol = col >> 5, vv = col & 31;
        float scv = scaleArr[64 + vv], shv = shiftArr[64 + vv];
        const float* lc = lamcraw + ((size_t)(b0 + bcol) * 16) * 32 + vv;
#pragma unroll
        for (int i = 0; i < 4; ++i) {
            int row_b = (wm << 6) + (i << 4) + (qq << 2);
#pragma unroll
            for (int r = 0; r < 4; ++r) {
                int row = row_b + r;
                float lamc = scv * lc[(row & 15) * 32] + shv;
                sm.Ybf[row * 132 + col] = f2bf(acc[i][j][r] + lamc);
            }
        }
    }
    __syncthreads();

    // epilogue: thread owns (b, h, v0..v0+1); out[b][h*32+v][n] = sum_k (q*sc+sh)*Y
    int c0 = t * 2;
    int bb2 = c0 >> 7;
    int hh = (c0 >> 5) & 3;
    int v0 = c0 & 31;
    int bglob = b0 + bb2;
    float o0[8], o1[8];
#pragma unroll
    for (int nn = 0; nn < 8; ++nn) { o0[nn] = 0.f; o1[nn] = 0.f; }
    const float* qsrc = qraw + ((size_t)bglob * 64 + hh * 16) * 1024 + mtile * 8;
#pragma unroll
    for (int k = 0; k < 16; ++k) {
        float4 qa = *(const float4*)(qsrc + (size_t)k * 1024);
        float4 qb4 = *(const float4*)(qsrc + (size_t)k * 1024 + 4);
        float sc = scaleArr[hh * 16 + k], sh = shiftArr[hh * 16 + k];
        float qv[8] = {qa.x, qa.y, qa.z, qa.w, qb4.x, qb4.y, qb4.z, qb4.w};
#pragma unroll
        for (int nn = 0; nn < 8; ++nn) {
            float qn = qv[nn] * sc + sh;
            unsigned yp = *(const unsigned*)&sm.Ybf[(nn * 16 + k) * 132 + bb2 * 32 + v0];
            o0[nn] += qn * bf2f((unsigned short)(yp & 0xffff));
            o1[nn] += qn * bf2f((unsigned short)(yp >> 16));
        }
    }
    float* op = out + ((size_t)bglob * 128 + hh * 32 + v0) * 1024 + mtile * 8;
    ((float4*)op)[0] = make_float4(o0[0], o0[1], o0[2], o0[3]);
    ((float4*)op)[1] = make_float4(o0[4], o0[5], o0[6], o0[7]);
    float* op1 = op + 1024;
    ((float4*)op1)[0] = make_float4(o1[0], o1[1], o1[2], o1[3]);
    ((float4*)op1)[1] = make_float4(o1[4], o1[5], o1[6], o1[7]);
}

// ---------------------------------------------------------------- launch
extern "C" void kernel_launch(void* const* d_in, const int* in_sizes, int n_in,
                              void* d_out, int out_size, void* d_ws, size_t ws_size,
                              hipStream_t stream) {
    const float* x   = (const float*)d_in[0];
    const float* wq  = (const float*)d_in[1];
    const float* wk  = (const float*)d_in[2];
    const float* wv  = (const float*)d_in[3];
    const float* pos = (const float*)d_in[4];
    const float* gq  = (const float*)d_in[5];
    const float* bq  = (const float*)d_in[6];
    const float* gv  = (const float*)d_in[7];
    const float* bv  = (const float*)d_in[8];
    float* out = (float*)d_out;

    char* ws = (char*)d_ws;
    float* qraw          = (float*)(ws);                    // 4 MB
    float* kraw          = (float*)(ws + 4194304);          // 1 MB
    float* vraw          = (float*)(ws + 5242880);          // 2 MB
    unsigned short* vbn  = (unsigned short*)(ws + 7340032); // 1 MB
    float* lamcraw       = (float*)(ws + 8388608);          // 32 KB
    float* scaleArr      = (float*)(ws + 8421376);          // 512 B
    float* shiftArr      = (float*)(ws + 8421888);          // 512 B

    k_proj<<<dim3(32, 16), dim3(256), 0, stream>>>(x, wq, wk, wv, qraw, kraw, vraw);
    k_mid<<<dim3(352), dim3(1024), 0, stream>>>(qraw, kraw, vraw, gq, bq, gv, bv,
                                                vbn, scaleArr, shiftArr, lamcraw);
    k_lamp<<<dim3(128, 4), dim3(256), 0, stream>>>(pos, vbn, qraw, lamcraw,
                                                   scaleArr, shiftArr, out);
}

// Round 8
// 182.887 us; speedup vs baseline: 1.2139x; 1.2139x over previous
//
#include <hip/hip_runtime.h>
#include <hip/hip_bf16.h>
#include <cstdint>

// LambdaLayer on MI355X. b=16, dim=256, n=m=1024, HEADS=4, DIM_K=16, DIM_V=32.
// Pipeline (3 launches). NOTE: harness adds ~114us fixed overhead per timed iter
// (256MiB ws re-poison + input restore) -> only kernel-sum is optimizable.
//   k_front: blocks 0..511: proj GEMM (112x256)@(256x32) -> qraw/kraw/vraw fp32
//            (weights converted inline); blocks 512..1535: pos[n][m][k] fp32 ->
//            Pbf[(n*16+k)][m] bf16 (LDS transpose, coalesced both sides).
//   k_mid  : blocks 0..95: BN stats -> scale/shift; v-ch also write vbn bf16.
//            blocks 96..351: softmax(kraw) + lamcraw = sm . vraw.
//   k_lamp : R2-proven GEMM lam_p = Pbf(16384x1024) @ vbn^T(1024x512), BK=64 LDS
//            double-buffer (prefetch-before-compute), 64KB union; epilogue folds
//            BN(q) + lam_c: out = (q*sc+sh) . (lam_p + sc_v*lamcraw + sh_v).

typedef __attribute__((ext_vector_type(8))) __bf16 bf16x8;
typedef __attribute__((ext_vector_type(4))) float f32x4;

__device__ __forceinline__ unsigned short f2bf(float f) {
    unsigned u = __float_as_uint(f);
    u += 0x7fffu + ((u >> 16) & 1u);   // round-to-nearest-even
    return (unsigned short)(u >> 16);
}
__device__ __forceinline__ unsigned pk2(float a, float b) {
    return (unsigned)f2bf(a) | ((unsigned)f2bf(b) << 16);
}
__device__ __forceinline__ float bf2f(unsigned short h) {
    return __uint_as_float(((unsigned)h) << 16);
}
__device__ __forceinline__ void async16(const void* g, void* l) {
    __builtin_amdgcn_global_load_lds(
        (const __attribute__((address_space(1))) void*)g,
        (__attribute__((address_space(3))) void*)l, 16, 0, 0);
}

// ---------------------------------------------------------------- k_front
// blocks 0..511: proj (bx=blk: b=bx>>5, px0=(bx&31)*32)
// blocks 512..1535: transp of pos row n=blk-512
__global__ __launch_bounds__(256) void k_front(const float* __restrict__ pos,
                                               unsigned* __restrict__ PbfU,
                                               const float* __restrict__ x,
                                               const float* __restrict__ wq,
                                               const float* __restrict__ wk,
                                               const float* __restrict__ wv,
                                               float* __restrict__ qraw,
                                               float* __restrict__ kraw,
                                               float* __restrict__ vraw) {
    int blk = blockIdx.x;
    int t = threadIdx.x;

    __shared__ union {
        __align__(16) unsigned short L[16 * 1032];                                   // transp: 33KB
        struct { __align__(16) unsigned short Al[128 * 32], Bl[32 * 34]; } pj;       // proj: 18.6KB
    } sm;

    if (blk >= 512) {   // ---- transpose path (R2-proven)
        int n = blk - 512;
        const float4* src = (const float4*)(pos + (size_t)n * 16384);
#pragma unroll
        for (int r = 0; r < 16; ++r) {
            int idx4 = r * 256 + t;           // 0..4095 float4s
            float4 f = src[idx4];
            int m = idx4 >> 2, k0 = (idx4 & 3) << 2;
            sm.L[(k0 + 0) * 1032 + m] = f2bf(f.x);
            sm.L[(k0 + 1) * 1032 + m] = f2bf(f.y);
            sm.L[(k0 + 2) * 1032 + m] = f2bf(f.z);
            sm.L[(k0 + 3) * 1032 + m] = f2bf(f.w);
        }
        __syncthreads();
        uint2* dst = (uint2*)(PbfU + (size_t)n * 8192);
#pragma unroll
        for (int r = 0; r < 16; ++r) {
            int c = r * 256 + t;              // uint2 chunk 0..4095
            int k = c >> 8, mo = c & 255;
            dst[c] = *(const uint2*)&sm.L[k * 1032 + mo * 4];
        }
        return;
    }

    // ---- proj path
    int b = blk >> 5;
    int px0 = (blk & 31) * 32;
    int w = t >> 6, lane = t & 63;

    int ch = t >> 1, half = t & 1;
    const float* wsrc = nullptr;
    if (ch < 64)       wsrc = wq + ch * 256;
    else if (ch < 80)  wsrc = wk + (ch - 64) * 256;
    else if (ch < 112) wsrc = wv + (ch - 80) * 256;
    if (wsrc) wsrc += half * 16;
    int s2 = (ch >> 1) & 3;
    unsigned short* wdst0 = &sm.pj.Al[ch * 32 + (((half * 2) ^ s2) << 3)];
    unsigned short* wdst1 = &sm.pj.Al[ch * 32 + (((half * 2 + 1) ^ s2) << 3)];

    int wm = w >> 1, wn = w & 1;
    int rl = lane & 15, qq = lane >> 4;
    int sw = qq ^ ((rl >> 1) & 3);

    f32x4 acc[4];
#pragma unroll
    for (int i = 0; i < 4; ++i)
#pragma unroll
        for (int r = 0; r < 4; ++r) acc[i][r] = 0.f;

    const float* xb = x + (size_t)b * 262144 + px0;

    for (int kt = 0; kt < 8; ++kt) {
        int c0 = kt * 32;
        {
            uint4 d0, d1;
            if (wsrc) {
                float4 f0 = *(const float4*)(wsrc + c0);
                float4 f1 = *(const float4*)(wsrc + c0 + 4);
                float4 f2 = *(const float4*)(wsrc + c0 + 8);
                float4 f3 = *(const float4*)(wsrc + c0 + 12);
                d0.x = pk2(f0.x, f0.y); d0.y = pk2(f0.z, f0.w);
                d0.z = pk2(f1.x, f1.y); d0.w = pk2(f1.z, f1.w);
                d1.x = pk2(f2.x, f2.y); d1.y = pk2(f2.z, f2.w);
                d1.z = pk2(f3.x, f3.y); d1.w = pk2(f3.z, f3.w);
            } else {
                d0 = make_uint4(0, 0, 0, 0); d1 = d0;
            }
            *(uint4*)wdst0 = d0;
            *(uint4*)wdst1 = d1;
        }
#pragma unroll
        for (int rep = 0; rep < 2; ++rep) {
            int idx = rep * 256 + t;
            int px = idx & 31;
            int cp = idx >> 5;
            int c = c0 + cp * 2;
            float f0 = xb[(size_t)c * 1024 + px];
            float f1 = xb[(size_t)(c + 1) * 1024 + px];
            *(unsigned*)&sm.pj.Bl[px * 34 + cp * 2] = pk2(f0, f1);
        }
        __syncthreads();
        bf16x8 a[4], bb;
#pragma unroll
        for (int i = 0; i < 4; ++i) a[i] = *(const bf16x8*)&sm.pj.Al[((wm << 6) + (i << 4) + rl) * 32 + sw * 8];
        bb = *(const bf16x8*)&sm.pj.Bl[((wn << 4) + rl) * 34 + qq * 8];
#pragma unroll
        for (int i = 0; i < 4; ++i)
            acc[i] = __builtin_amdgcn_mfma_f32_16x16x32_bf16(a[i], bb, acc[i], 0, 0, 0);
        __syncthreads();
    }

#pragma unroll
    for (int i = 0; i < 4; ++i) {
        int px = px0 + (wn << 4) + rl;
#pragma unroll
        for (int r = 0; r < 4; ++r) {
            int c = (wm << 6) + (i << 4) + (qq << 2) + r;
            float val = acc[i][r];
            if (c < 64)       qraw[((size_t)b * 64 + c) * 1024 + px] = val;
            else if (c < 80)  kraw[((size_t)b * 16 + (c - 64)) * 1024 + px] = val;
            else if (c < 112) vraw[((size_t)b * 32 + (c - 80)) * 1024 + px] = val;
        }
    }
}

// ---------------------------------------------------------------- k_mid
__global__ __launch_bounds__(1024) void k_mid(const float* __restrict__ qraw,
                                              const float* __restrict__ kraw,
                                              const float* __restrict__ vraw,
                                              const float* __restrict__ gq, const float* __restrict__ bq,
                                              const float* __restrict__ gv, const float* __restrict__ bv,
                                              unsigned short* __restrict__ vbn,
                                              float* __restrict__ scaleArr, float* __restrict__ shiftArr,
                                              float* __restrict__ lamcraw) {
    int bx = blockIdx.x;
    int t = threadIdx.x;
    int w = t >> 6, lane = t & 63;
    __shared__ float redA[16], redB[16];
    __shared__ float bc[2];
    __shared__ float pr[16][32];

    if (bx < 96) {
        int ch = bx;
        const float* base;
        size_t bstride;
        if (ch < 64) { base = qraw + (size_t)ch * 1024; bstride = 65536; }
        else         { base = vraw + (size_t)(ch - 64) * 1024; bstride = 32768; }
        float s = 0.f, ss = 0.f;
#pragma unroll
        for (int b = 0; b < 16; ++b) { float v = base[b * bstride + t]; s += v; ss += v * v; }
#pragma unroll
        for (int off = 32; off; off >>= 1) { s += __shfl_down(s, off); ss += __shfl_down(ss, off); }
        if (lane == 0) { redA[w] = s; redB[w] = ss; }
        __syncthreads();
        if (t == 0) {
            s = 0.f; ss = 0.f;
#pragma unroll
            for (int i = 0; i < 16; ++i) { s += redA[i]; ss += redB[i]; }
            float mean = s * (1.f / 16384.f);
            float var = ss * (1.f / 16384.f) - mean * mean;   // biased (jnp.var)
            float g, be;
            if (ch < 64) { g = gq[ch]; be = bq[ch]; } else { g = gv[ch - 64]; be = bv[ch - 64]; }
            float sc = g * rsqrtf(var + 1e-5f);
            float sh = be - mean * sc;
            scaleArr[ch] = sc; shiftArr[ch] = sh;
            bc[0] = sc; bc[1] = sh;
        }
        __syncthreads();
        if (ch >= 64) {
            float sc = bc[0], sh = bc[1];
            int vch = ch - 64;
#pragma unroll
            for (int b = 0; b < 16; ++b) {
                size_t idx = ((size_t)b * 32 + vch) * 1024 + t;
                vbn[idx] = f2bf(vraw[idx] * sc + sh);
            }
        }
    } else {
        int idx = bx - 96;
        int b = idx >> 4, kch = idx & 15;
        float xv = kraw[((size_t)b * 16 + kch) * 1024 + t];
        float mx = xv;
#pragma unroll
        for (int off = 32; off; off >>= 1) mx = fmaxf(mx, __shfl_down(mx, off));
        if (lane == 0) redA[w] = mx;
        __syncthreads();
        mx = redA[0];
#pragma unroll
        for (int i = 1; i < 16; ++i) mx = fmaxf(mx, redA[i]);
        float e = __expf(xv - mx);
        float s = e;
#pragma unroll
        for (int off = 32; off; off >>= 1) s += __shfl_down(s, off);
        __syncthreads();
        if (lane == 0) redB[w] = s;
        __syncthreads();
        s = 0.f;
#pragma unroll
        for (int i = 0; i < 16; ++i) s += redB[i];
        float inv = 1.f / s;
        const float* vb = vraw + (size_t)b * 32768;
        for (int v = 0; v < 32; ++v) {
            float p = e * vb[(size_t)v * 1024 + t];
#pragma unroll
            for (int off = 32; off; off >>= 1) p += __shfl_down(p, off);
            if (lane == 0) pr[w][v] = p;
        }
        __syncthreads();
        if (t < 32) {
            float tot = 0.f;
#pragma unroll
            for (int i = 0; i < 16; ++i) tot += pr[i][t];
            lamcraw[((size_t)b * 16 + kch) * 32 + t] = inv * tot;
        }
    }
}

// ---------------------------------------------------------------- k_lamp
// R2-proven: GEMM M=16384, N=512, K=1024; grid(128,4), ntile siblings same XCD.
// BK=64, LDS double-buffer (st[0..1]=buf0 A,B; st[2..3]=buf1), prefetch issued
// before compute, one barrier per iter. 64KB union with fp32 Y.
__global__ __launch_bounds__(256) void k_lamp(const unsigned short* __restrict__ Pbf,
                                              const unsigned short* __restrict__ vbn,
                                              const float* __restrict__ qraw,
                                              const float* __restrict__ lamcraw,
                                              const float* __restrict__ scaleArr,
                                              const float* __restrict__ shiftArr,
                                              float* __restrict__ out) {
    int mtile = blockIdx.x;    // 0..127
    int ntile = blockIdx.y;    // 0..3
    int t = threadIdx.x;
    int w = t >> 6, lane = t & 63;

    __shared__ union {
        __align__(16) unsigned short st[4][8192];   // A0,B0,A1,B1 (16KB each)
        float Y[128 * 128];                         // 64KB epilogue buffer
    } sm;

    // staging: wave w covers rows w*32..w*32+31; octet XOR-swizzled by row&7.
    int roff = lane >> 3;
    int jx = (lane & 7) ^ (roff & 7);
    const unsigned short* pA[4];
    const unsigned short* pB[4];
#pragma unroll
    for (int i = 0; i < 4; ++i) {
        int rowA = mtile * 128 + w * 32 + i * 8 + roff;
        int rowB = ntile * 128 + w * 32 + i * 8 + roff;
        pA[i] = Pbf + (size_t)rowA * 1024 + jx * 8;
        pB[i] = vbn + (size_t)rowB * 1024 + jx * 8;
    }

    int wm = w >> 1, wn = w & 1;
    int rl = lane & 15, qq = lane >> 4;
    int aoff[2][4], boff[2][4];
#pragma unroll
    for (int ks = 0; ks < 2; ++ks)
#pragma unroll
        for (int i = 0; i < 4; ++i) {
            int rowA = wm * 64 + i * 16 + rl;
            aoff[ks][i] = rowA * 64 + (((ks * 4 + qq) ^ (rowA & 7)) << 3);
            int rowB = wn * 64 + i * 16 + rl;
            boff[ks][i] = rowB * 64 + (((ks * 4 + qq) ^ (rowB & 7)) << 3);
        }

    f32x4 acc[4][4];
#pragma unroll
    for (int i = 0; i < 4; ++i)
#pragma unroll
        for (int j = 0; j < 4; ++j)
#pragma unroll
            for (int r = 0; r < 4; ++r) acc[i][j][r] = 0.f;

    auto stage = [&](int s, int kk) {   // s = 0 or 2 (buffer base in st[] units)
        unsigned short* dstA = &sm.st[s][0];
        unsigned short* dstB = &sm.st[s + 1][0];
#pragma unroll
        for (int i = 0; i < 4; ++i) {
            async16(pA[i] + kk * 64, dstA + w * 2048 + i * 512);
            async16(pB[i] + kk * 64, dstB + w * 2048 + i * 512);
        }
    };

    stage(0, 0);
    __syncthreads();

    for (int kt = 0; kt < 16; ++kt) {
        int cur = (kt & 1) ? 2 : 0;
        if (kt < 15) stage(cur ^ 2, kt + 1);   // prefetch in flight during compute
        const unsigned short* curA = &sm.st[cur][0];
        const unsigned short* curB = &sm.st[cur + 1][0];
#pragma unroll
        for (int ks = 0; ks < 2; ++ks) {
            bf16x8 a[4], bb[4];
#pragma unroll
            for (int i = 0; i < 4; ++i) a[i]  = *(const bf16x8*)&curA[aoff[ks][i]];
#pragma unroll
            for (int j = 0; j < 4; ++j) bb[j] = *(const bf16x8*)&curB[boff[ks][j]];
#pragma unroll
            for (int i = 0; i < 4; ++i)
#pragma unroll
                for (int j = 0; j < 4; ++j)
                    acc[i][j] = __builtin_amdgcn_mfma_f32_16x16x32_bf16(a[i], bb[j], acc[i][j], 0, 0, 0);
        }
        __syncthreads();
    }

    // acc + (sc_v*lamcraw + sh_v) -> Y fp32 (stride 128)
    int b0 = ntile * 4;
#pragma unroll
    for (int j = 0; j < 4; ++j) {
        int col = (wn << 6) + (j << 4) + rl;
        int bcol = col >> 5, vv = col & 31;
        float scv = scaleArr[64 + vv], shv = shiftArr[64 + vv];
        const float* lc = lamcraw + ((size_t)(b0 + bcol) * 16) * 32 + vv;
#pragma unroll
        for (int i = 0; i < 4; ++i) {
            int row_b = (wm << 6) + (i << 4) + (qq << 2);
#pragma unroll
            for (int r = 0; r < 4; ++r) {
                int row = row_b + r;
                sm.Y[row * 128 + col] = acc[i][j][r] + scv * lc[(row & 15) * 32] + shv;
            }
        }
    }
    __syncthreads();

    // epilogue: thread owns (b, h, v0..v0+1); out[b][h*32+v][n] = sum_k (q*sc+sh)*Y
    int c0 = t * 2;
    int bb2 = c0 >> 7;
    int hh = (c0 >> 5) & 3;
    int v0 = c0 & 31;
    int bglob = b0 + bb2;
    float o0[8], o1[8];
#pragma unroll
    for (int nn = 0; nn < 8; ++nn) { o0[nn] = 0.f; o1[nn] = 0.f; }
    const float* qsrc = qraw + ((size_t)bglob * 64 + hh * 16) * 1024 + mtile * 8;
#pragma unroll
    for (int k = 0; k < 16; ++k) {
        float4 qa = *(const float4*)(qsrc + (size_t)k * 1024);
        float4 qb4 = *(const float4*)(qsrc + (size_t)k * 1024 + 4);
        float sc = scaleArr[hh * 16 + k], sh = shiftArr[hh * 16 + k];
        float qv[8] = {qa.x, qa.y, qa.z, qa.w, qb4.x, qb4.y, qb4.z, qb4.w};
        const float* yrow = &sm.Y[k * 128 + bb2 * 32 + v0];
#pragma unroll
        for (int nn = 0; nn < 8; ++nn) {
            float qn = qv[nn] * sc + sh;
            o0[nn] += qn * yrow[nn * 16 * 128];
            o1[nn] += qn * yrow[nn * 16 * 128 + 1];
        }
    }
    float* op = out + ((size_t)bglob * 128 + hh * 32 + v0) * 1024 + mtile * 8;
    ((float4*)op)[0] = make_float4(o0[0], o0[1], o0[2], o0[3]);
    ((float4*)op)[1] = make_float4(o0[4], o0[5], o0[6], o0[7]);
    float* op1 = op + 1024;
    ((float4*)op1)[0] = make_float4(o1[0], o1[1], o1[2], o1[3]);
    ((float4*)op1)[1] = make_float4(o1[4], o1[5], o1[6], o1[7]);
}

// ---------------------------------------------------------------- launch
extern "C" void kernel_launch(void* const* d_in, const int* in_sizes, int n_in,
                              void* d_out, int out_size, void* d_ws, size_t ws_size,
                              hipStream_t stream) {
    const float* x   = (const float*)d_in[0];
    const float* wq  = (const float*)d_in[1];
    const float* wk  = (const float*)d_in[2];
    const float* wv  = (const float*)d_in[3];
    const float* pos = (const float*)d_in[4];
    const float* gq  = (const float*)d_in[5];
    const float* bq  = (const float*)d_in[6];
    const float* gv  = (const float*)d_in[7];
    const float* bv  = (const float*)d_in[8];
    float* out = (float*)d_out;

    char* ws = (char*)d_ws;
    unsigned short* Pbf  = (unsigned short*)(ws);            // 32 MB
    float* qraw          = (float*)(ws + 33554432);          // 4 MB
    float* kraw          = (float*)(ws + 37748736);          // 1 MB
    float* vraw          = (float*)(ws + 38797312);          // 2 MB
    unsigned short* vbn  = (unsigned short*)(ws + 40894464); // 1 MB
    float* lamcraw       = (float*)(ws + 41943040);          // 32 KB
    float* scaleArr      = (float*)(ws + 41975808);          // 512 B
    float* shiftArr      = (float*)(ws + 41976320);          // 512 B

    k_front<<<dim3(1536), dim3(256), 0, stream>>>(pos, (unsigned*)Pbf, x, wq, wk, wv,
                                                  qraw, kraw, vraw);
    k_mid<<<dim3(352), dim3(1024), 0, stream>>>(qraw, kraw, vraw, gq, bq, gv, bv,
                                                vbn, scaleArr, shiftArr, lamcraw);
    k_lamp<<<dim3(128, 4), dim3(256), 0, stream>>>(Pbf, vbn, qraw, lamcraw,
                                                   scaleArr, shiftArr, out);
}